// Round 6
// baseline (118.371 us; speedup 1.0000x reference)
//
#include <hip/hip_runtime.h>
#include <hip/hip_bf16.h>

typedef __attribute__((ext_vector_type(8))) short short8;
typedef __attribute__((ext_vector_type(4))) float f32x4;

#define CIN   16
#define COUT  64
#define HH    256
#define WW    256
#define OHH   254
#define OWW   254

// LDS patch: [2 cihalf][34 h][36 w][8 ci] bf16. 16B cells; w padded 34->36 so
// quad-staging overhang lands in dead cells. Total 39,168 B -> 4 blocks/CU.
#define HSTR   (36 * 8)            // ushorts per h row within one half
#define HALFU  (34 * HSTR)         // ushorts per ci-half

__device__ __forceinline__ ushort f2bf(float f) {
    unsigned u = __builtin_bit_cast(unsigned, f);
    unsigned r = (u + 0x7fffu + ((u >> 16) & 1u)) >> 16;
    return (ushort)r;
}

// fast tanh(tanh(x)): exp2-based (verified absmax 3.9e-3 in R1-R5)
__device__ __forceinline__ float dtanh2(float x) {
    const float K = 2.8853900817779268f;   // 2*log2(e)
    float xc = fminf(fmaxf(x, -9.0f), 9.0f);
    float e1 = __builtin_amdgcn_exp2f(K * xc);
    float t1 = 1.0f - 2.0f * __builtin_amdgcn_rcpf(e1 + 1.0f);
    float e2 = __builtin_amdgcn_exp2f(K * t1);
    return 1.0f - 2.0f * __builtin_amdgcn_rcpf(e2 + 1.0f);
}

// Weights fp32 OIHW [64][16][3][3] -> per-lane bf16 A-fragments:
// wfrag[p][j][lane][r]: k_local = 8*(lane>>4)+r, tap = 2p + (k_local>=16),
// ci = k_local&15, channel = 16j + (lane&15). tap==9 -> 0.
__global__ void prep_weights(const float* __restrict__ wsrc, ushort* __restrict__ wfrag) {
    int idx = blockIdx.x * 256 + threadIdx.x;
    if (idx >= 10240) return;
    int r    = idx & 7;
    int lane = (idx >> 3) & 63;
    int j    = (idx >> 9) & 3;
    int p    = idx >> 11;
    int kl   = ((lane >> 4) << 3) + r;
    int tap  = 2 * p + (kl >> 4);
    int ci   = kl & 15;
    int co   = j * 16 + (lane & 15);
    float v = 0.0f;
    if (tap <= 8) {
        int kh = tap / 3, kw = tap - 3 * (tap / 3);
        v = wsrc[(co * CIN + ci) * 9 + kh * 3 + kw];
    }
    wfrag[idx] = f2bf(v);
}

__global__ __launch_bounds__(256, 4) void conv_min_tanh(
        const float* __restrict__ x, const ushort* __restrict__ wfrag,
        const float* __restrict__ bias, float* __restrict__ out) {
    __shared__ ushort lds[2 * HALFU];        // 39,168 B

    const int tid = threadIdx.x;
    const int n   = blockIdx.z;
    const int oh0 = blockIdx.y * 32;
    const int ow0 = blockIdx.x * 32;
    const int HW  = HH * WW;

    // ---- stage 34x34x16ci patch with float4 loads + b64 LDS writes ----
    // position = (hp 0..33, ciq 0..3, w4 0..8): load float4 of 4 w for ci=4ciq..4ciq+3
    const float* xb = x + (size_t)n * CIN * HW;
    auto stage_pos = [&](int pos) {
        int hp  = pos / 36;                  // 34 rows
        int r2  = pos - hp * 36;
        int ciq = r2 / 9;                    // ci quad
        int w4  = r2 - ciq * 9;              // w quad (covers w 4*w4..4*w4+3)
        int hg  = min(oh0 + hp, HH - 1);     // clamped edges; outputs masked later
        int wg  = min(ow0 + 4 * w4, WW - 4); // clamped, stays 16B aligned
        const float* src = xb + (size_t)(ciq * 4) * HW + hg * WW + wg;
        f32x4 v0 = *reinterpret_cast<const f32x4*>(src);
        f32x4 v1 = *reinterpret_cast<const f32x4*>(src + HW);
        f32x4 v2 = *reinterpret_cast<const f32x4*>(src + 2 * HW);
        f32x4 v3 = *reinterpret_cast<const f32x4*>(src + 3 * HW);
        ushort* dst = &lds[(ciq >> 1) * HALFU + (hp * 36 + 4 * w4) * 8 + (ciq & 1) * 4];
#pragma unroll
        for (int e = 0; e < 4; ++e) {        // one 8B write per w cell: ci quad contiguous
            unsigned lo, hi;
            asm("v_cvt_pk_bf16_f32 %0, %1, %2" : "=v"(lo) : "v"(v0[e]), "v"(v1[e]));
            asm("v_cvt_pk_bf16_f32 %0, %1, %2" : "=v"(hi) : "v"(v2[e]), "v"(v3[e]));
            uint2 pk; pk.x = lo; pk.y = hi;
            *reinterpret_cast<uint2*>(dst + e * 8) = pk;
        }
    };
#pragma unroll
    for (int it = 0; it < 4; ++it) stage_pos(tid + it * 256);
    if (tid < 1224 - 1024) stage_pos(tid + 1024);

    const int lane = tid & 63;
    const int wid  = tid >> 6;
    const int g    = lane >> 4;
    const int mm   = lane & 15;

    // ---- all 4 weight tiles (A-operand) -> registers (80 VGPRs) ----
    short8 wf0[5], wf1[5], wf2[5], wf3[5];
#pragma unroll
    for (int p = 0; p < 5; ++p) {
        wf0[p] = *reinterpret_cast<const short8*>(wfrag + (((p * 4 + 0) * 64 + lane) * 8));
        wf1[p] = *reinterpret_cast<const short8*>(wfrag + (((p * 4 + 1) * 64 + lane) * 8));
        wf2[p] = *reinterpret_cast<const short8*>(wfrag + (((p * 4 + 2) * 64 + lane) * 8));
        wf3[p] = *reinterpret_cast<const short8*>(wfrag + (((p * 4 + 3) * 64 + lane) * 8));
    }
    // bias into acc init: D row = channel-in-tile = 4g+r
    const f32x4 bi0 = *reinterpret_cast<const f32x4*>(bias +  0 + 4 * g);
    const f32x4 bi1 = *reinterpret_cast<const f32x4*>(bias + 16 + 4 * g);
    const f32x4 bi2 = *reinterpret_cast<const f32x4*>(bias + 32 + 4 * g);
    const f32x4 bi3 = *reinterpret_cast<const f32x4*>(bias + 48 + 4 * g);

    __syncthreads();

    // ---- each wave: rows wid*8..wid*8+7, 2 colhalves; 20 MFMA per pixel-group ----
#pragma unroll
    for (int ch = 0; ch < 2; ++ch) {
        const ushort* bp[5];
#pragma unroll
        for (int p = 0; p < 5; ++p) {
            int tap = 2 * p + (g >> 1);
            if (tap > 8) tap = 8;             // pair-4 upper half: weights are zero there
            int kh = tap / 3, kw = tap - 3 * (tap / 3);
            bp[p] = &lds[(g & 1) * HALFU + (wid * 8 + kh) * HSTR + (ch * 16 + mm + kw) * 8];
        }
#pragma unroll
        for (int i = 0; i < 8; ++i) {
            f32x4 a0 = bi0, a1 = bi1, a2 = bi2, a3 = bi3;
#pragma unroll
            for (int p = 0; p < 5; ++p) {
                short8 b = *reinterpret_cast<const short8*>(bp[p] + i * HSTR);
                a0 = __builtin_amdgcn_mfma_f32_16x16x32_bf16(wf0[p], b, a0, 0, 0, 0);
                a1 = __builtin_amdgcn_mfma_f32_16x16x32_bf16(wf1[p], b, a1, 0, 0, 0);
                a2 = __builtin_amdgcn_mfma_f32_16x16x32_bf16(wf2[p], b, a2, 0, 0, 0);
                a3 = __builtin_amdgcn_mfma_f32_16x16x32_bf16(wf3[p], b, a3, 0, 0, 0);
            }
            // in-lane min over 16 channels, then cross-group (xor16, xor32)
            float v = fminf(fminf(fminf(a0[0], a0[1]), fminf(a0[2], a0[3])),
                            fminf(fminf(a1[0], a1[1]), fminf(a1[2], a1[3])));
            v = fminf(v, fminf(fminf(fminf(a2[0], a2[1]), fminf(a2[2], a2[3])),
                               fminf(fminf(a3[0], a3[1]), fminf(a3[2], a3[3]))));
            v = fminf(v, __shfl_xor(v, 16, 64));
            v = fminf(v, __shfl_xor(v, 32, 64));
            const float y = dtanh2(v);
            const int oh = oh0 + wid * 8 + i;
            const int ow = ow0 + ch * 16 + mm;
            if (lane < 16 && oh < OHH && ow < OWW)
                out[((size_t)n * OHH + oh) * OWW + ow] = y;
        }
    }
}

extern "C" void kernel_launch(void* const* d_in, const int* in_sizes, int n_in,
                              void* d_out, int out_size, void* d_ws, size_t ws_size,
                              hipStream_t stream) {
    const float* x = (const float*)d_in[0];
    const float* w = (const float*)d_in[1];
    const float* b = (const float*)d_in[2];
    float* out     = (float*)d_out;
    ushort* wfrag  = (ushort*)d_ws;          // 20 KiB

    prep_weights<<<40, 256, 0, stream>>>(w, wfrag);
    dim3 grid(8, 8, 32);                     // (owT, ohT, n), 32x32 tiles
    conv_min_tanh<<<grid, dim3(256, 1, 1), 0, stream>>>(x, wfrag, b, out);
}

// Round 7
// 61.783 us; speedup vs baseline: 1.9159x; 1.9159x over previous
//
#include <hip/hip_runtime.h>
#include <hip/hip_bf16.h>

typedef __attribute__((ext_vector_type(8))) short short8;
typedef __attribute__((ext_vector_type(4))) float f32x4;

#define CIN   16
#define COUT  64
#define HH    256
#define WW    256
#define OHH   254
#define OWW   254

// LDS patch: [2 cihalf][34 h][36 w][8 ci] bf16. 16B cells; w padded 34->36 so
// quad-staging overhang lands in dead cells. Total 39,168 B.
#define HSTR   (36 * 8)            // ushorts per h row within one half
#define HALFU  (34 * HSTR)         // ushorts per ci-half

__device__ __forceinline__ ushort f2bf(float f) {
    unsigned u = __builtin_bit_cast(unsigned, f);
    unsigned r = (u + 0x7fffu + ((u >> 16) & 1u)) >> 16;
    return (ushort)r;
}

// fast tanh(tanh(x)): exp2-based (verified absmax 3.9e-3 in R1-R6)
__device__ __forceinline__ float dtanh2(float x) {
    const float K = 2.8853900817779268f;   // 2*log2(e)
    float xc = fminf(fmaxf(x, -9.0f), 9.0f);
    float e1 = __builtin_amdgcn_exp2f(K * xc);
    float t1 = 1.0f - 2.0f * __builtin_amdgcn_rcpf(e1 + 1.0f);
    float e2 = __builtin_amdgcn_exp2f(K * t1);
    return 1.0f - 2.0f * __builtin_amdgcn_rcpf(e2 + 1.0f);
}

// Weights fp32 OIHW [64][16][3][3] -> per-lane bf16 A-fragments:
// wfrag[p][j][lane][r]: k_local = 8*(lane>>4)+r, tap = 2p + (k_local>=16),
// ci = k_local&15, channel = 16j + (lane&15). tap==9 -> 0.
__global__ void prep_weights(const float* __restrict__ wsrc, ushort* __restrict__ wfrag) {
    int idx = blockIdx.x * 256 + threadIdx.x;
    if (idx >= 10240) return;
    int r    = idx & 7;
    int lane = (idx >> 3) & 63;
    int j    = (idx >> 9) & 3;
    int p    = idx >> 11;
    int kl   = ((lane >> 4) << 3) + r;
    int tap  = 2 * p + (kl >> 4);
    int ci   = kl & 15;
    int co   = j * 16 + (lane & 15);
    float v = 0.0f;
    if (tap <= 8) {
        int kh = tap / 3, kw = tap - 3 * (tap / 3);
        v = wsrc[(co * CIN + ci) * 9 + kh * 3 + kw];
    }
    wfrag[idx] = f2bf(v);
}

// NOTE: register working set ~150; any launch_bounds cap below that spills
// (R2: (256,4)->spill, R6: (256,4)->spill, 77MB scratch writes). Keep (256,3).
__global__ __launch_bounds__(256, 3) void conv_min_tanh(
        const float* __restrict__ x, const ushort* __restrict__ wfrag,
        const float* __restrict__ bias, float* __restrict__ out) {
    __shared__ ushort lds[2 * HALFU];        // 39,168 B

    const int tid = threadIdx.x;
    const int n   = blockIdx.z;
    const int oh0 = blockIdx.y * 32;
    const int ow0 = blockIdx.x * 32;
    const int HW  = HH * WW;

    // ---- stage 34x34x16ci patch with float4 loads + b64 LDS writes ----
    // position = (hp 0..33, ciq 0..3, w4 0..8): load float4 of 4 w for ci=4ciq..4ciq+3
    const float* xb = x + (size_t)n * CIN * HW;
    auto stage_pos = [&](int pos) {
        int hp  = pos / 36;                  // 34 rows
        int r2  = pos - hp * 36;
        int ciq = r2 / 9;                    // ci quad
        int w4  = r2 - ciq * 9;              // w quad (covers w 4*w4..4*w4+3)
        int hg  = min(oh0 + hp, HH - 1);     // clamped edges; outputs masked later
        int wg  = min(ow0 + 4 * w4, WW - 4); // clamped, stays 16B aligned
        const float* src = xb + (size_t)(ciq * 4) * HW + hg * WW + wg;
        f32x4 v0 = *reinterpret_cast<const f32x4*>(src);
        f32x4 v1 = *reinterpret_cast<const f32x4*>(src + HW);
        f32x4 v2 = *reinterpret_cast<const f32x4*>(src + 2 * HW);
        f32x4 v3 = *reinterpret_cast<const f32x4*>(src + 3 * HW);
        ushort* dst = &lds[(ciq >> 1) * HALFU + (hp * 36 + 4 * w4) * 8 + (ciq & 1) * 4];
#pragma unroll
        for (int e = 0; e < 4; ++e) {        // one 8B write per w cell: ci quad contiguous
            unsigned lo, hi;
            asm("v_cvt_pk_bf16_f32 %0, %1, %2" : "=v"(lo) : "v"(v0[e]), "v"(v1[e]));
            asm("v_cvt_pk_bf16_f32 %0, %1, %2" : "=v"(hi) : "v"(v2[e]), "v"(v3[e]));
            uint2 pk; pk.x = lo; pk.y = hi;
            *reinterpret_cast<uint2*>(dst + e * 8) = pk;
        }
    };
#pragma unroll
    for (int it = 0; it < 4; ++it) stage_pos(tid + it * 256);
    if (tid < 1224 - 1024) stage_pos(tid + 1024);

    const int lane = tid & 63;
    const int wid  = tid >> 6;
    const int g    = lane >> 4;
    const int mm   = lane & 15;

    // ---- all 4 weight tiles (A-operand) -> registers (80 VGPRs) ----
    short8 wf0[5], wf1[5], wf2[5], wf3[5];
#pragma unroll
    for (int p = 0; p < 5; ++p) {
        wf0[p] = *reinterpret_cast<const short8*>(wfrag + (((p * 4 + 0) * 64 + lane) * 8));
        wf1[p] = *reinterpret_cast<const short8*>(wfrag + (((p * 4 + 1) * 64 + lane) * 8));
        wf2[p] = *reinterpret_cast<const short8*>(wfrag + (((p * 4 + 2) * 64 + lane) * 8));
        wf3[p] = *reinterpret_cast<const short8*>(wfrag + (((p * 4 + 3) * 64 + lane) * 8));
    }
    // bias into acc init: D row = channel-in-tile = 4g+r
    const f32x4 bi0 = *reinterpret_cast<const f32x4*>(bias +  0 + 4 * g);
    const f32x4 bi1 = *reinterpret_cast<const f32x4*>(bias + 16 + 4 * g);
    const f32x4 bi2 = *reinterpret_cast<const f32x4*>(bias + 32 + 4 * g);
    const f32x4 bi3 = *reinterpret_cast<const f32x4*>(bias + 48 + 4 * g);

    __syncthreads();

    // ---- each wave: rows wid*8..wid*8+7, 2 colhalves; 20 MFMA per pixel-group ----
#pragma unroll
    for (int ch = 0; ch < 2; ++ch) {
        const ushort* bp[5];
#pragma unroll
        for (int p = 0; p < 5; ++p) {
            int tap = 2 * p + (g >> 1);
            if (tap > 8) tap = 8;             // pair-4 upper half: weights are zero there
            int kh = tap / 3, kw = tap - 3 * (tap / 3);
            bp[p] = &lds[(g & 1) * HALFU + (wid * 8 + kh) * HSTR + (ch * 16 + mm + kw) * 8];
        }
#pragma unroll
        for (int i = 0; i < 8; ++i) {
            f32x4 a0 = bi0, a1 = bi1, a2 = bi2, a3 = bi3;
#pragma unroll
            for (int p = 0; p < 5; ++p) {
                short8 b = *reinterpret_cast<const short8*>(bp[p] + i * HSTR);
                a0 = __builtin_amdgcn_mfma_f32_16x16x32_bf16(wf0[p], b, a0, 0, 0, 0);
                a1 = __builtin_amdgcn_mfma_f32_16x16x32_bf16(wf1[p], b, a1, 0, 0, 0);
                a2 = __builtin_amdgcn_mfma_f32_16x16x32_bf16(wf2[p], b, a2, 0, 0, 0);
                a3 = __builtin_amdgcn_mfma_f32_16x16x32_bf16(wf3[p], b, a3, 0, 0, 0);
            }
            // in-lane min over 16 channels, then cross-group (xor16, xor32)
            float v = fminf(fminf(fminf(a0[0], a0[1]), fminf(a0[2], a0[3])),
                            fminf(fminf(a1[0], a1[1]), fminf(a1[2], a1[3])));
            v = fminf(v, fminf(fminf(fminf(a2[0], a2[1]), fminf(a2[2], a2[3])),
                               fminf(fminf(a3[0], a3[1]), fminf(a3[2], a3[3]))));
            v = fminf(v, __shfl_xor(v, 16, 64));
            v = fminf(v, __shfl_xor(v, 32, 64));
            const float y = dtanh2(v);
            const int oh = oh0 + wid * 8 + i;
            const int ow = ow0 + ch * 16 + mm;
            if (lane < 16 && oh < OHH && ow < OWW)
                out[((size_t)n * OHH + oh) * OWW + ow] = y;
        }
    }
}

extern "C" void kernel_launch(void* const* d_in, const int* in_sizes, int n_in,
                              void* d_out, int out_size, void* d_ws, size_t ws_size,
                              hipStream_t stream) {
    const float* x = (const float*)d_in[0];
    const float* w = (const float*)d_in[1];
    const float* b = (const float*)d_in[2];
    float* out     = (float*)d_out;
    ushort* wfrag  = (ushort*)d_ws;          // 20 KiB

    prep_weights<<<40, 256, 0, stream>>>(w, wfrag);
    dim3 grid(8, 8, 32);                     // (owT, ohT, n), 32x32 tiles
    conv_min_tanh<<<grid, dim3(256, 1, 1), 0, stream>>>(x, wfrag, b, out);
}